// Round 1
// baseline (693.558 us; speedup 1.0000x reference)
//
#include <hip/hip_runtime.h>

// LIF multistep: T=4, VTHR=1.0, TAU=0.5, hard reset.
// x: (T, 32, 512, 1024) fp32.  Outputs: spikes (T*N), mems (T*N) concatenated.
// N = 16,777,216 elements per timestep.
// Memory-bound: 256 MiB read + 512 MiB write -> ~128 us roofline at 6.3 TB/s.

#define LIF_T 4

__global__ __launch_bounds__(256) void lif_kernel(
    const float4* __restrict__ x,
    float4* __restrict__ spikes,
    float4* __restrict__ mems,
    long n4)   // elements-per-timestep / 4
{
    long idx = (long)blockIdx.x * blockDim.x + threadIdx.x;
    if (idx >= n4) return;

    const float VTHR = 1.0f;
    const float TAU  = 0.5f;

    float v0 = 0.f, v1 = 0.f, v2 = 0.f, v3 = 0.f;

#pragma unroll
    for (int t = 0; t < LIF_T; ++t) {
        float4 xt = x[(size_t)t * n4 + idx];

        // integrate
        float u0 = v0 + xt.x;
        float u1 = v1 + xt.y;
        float u2 = v2 + xt.z;
        float u3 = v3 + xt.w;

        // spike (Heaviside of u - VTHR, strict >)
        float s0 = (u0 > VTHR) ? 1.f : 0.f;
        float s1 = (u1 > VTHR) ? 1.f : 0.f;
        float s2 = (u2 > VTHR) ? 1.f : 0.f;
        float s3 = (u3 > VTHR) ? 1.f : 0.f;

        // hard reset (v * (1 - s): exact zero when spiked, unchanged otherwise)
        u0 = (s0 > 0.f) ? 0.f : u0;
        u1 = (s1 > 0.f) ? 0.f : u1;
        u2 = (s2 > 0.f) ? 0.f : u2;
        u3 = (s3 > 0.f) ? 0.f : u3;

        // record spike & post-reset mem (pre-decay, per reference)
        spikes[(size_t)t * n4 + idx] = make_float4(s0, s1, s2, s3);
        mems[(size_t)t * n4 + idx]   = make_float4(u0, u1, u2, u3);

        // decay carried state
        v0 = u0 * TAU;
        v1 = u1 * TAU;
        v2 = u2 * TAU;
        v3 = u3 * TAU;
    }
}

extern "C" void kernel_launch(void* const* d_in, const int* in_sizes, int n_in,
                              void* d_out, int out_size, void* d_ws, size_t ws_size,
                              hipStream_t stream) {
    const float* x = (const float*)d_in[0];
    float* out = (float*)d_out;

    long total = (long)in_sizes[0];       // T * N
    long N = total / LIF_T;               // elements per timestep
    long n4 = N / 4;                      // float4 groups per timestep

    float4* spikes = (float4*)out;                     // first T*N floats
    float4* mems   = (float4*)(out + total);           // next T*N floats

    int block = 256;
    long grid = (n4 + block - 1) / block;

    lif_kernel<<<dim3((unsigned)grid), dim3(block), 0, stream>>>(
        (const float4*)x, spikes, mems, n4);
}